// Round 3
// baseline (4795.356 us; speedup 1.0000x reference)
//
#include <hip/hip_runtime.h>

#define SHF  32
#define TT   131072         // B*N tokens
#define SCALE 0.17677669529663687f

// ---------------- LayerNorm (+optional cyclic shift) ----------------
// one block per token (chunk-local), 256 threads = C channels.
// src row = t0+blockIdx.x rolled by SH within its 4096-token batch.
template <int SH>
__global__ __launch_bounds__(256) void ln_kernel(const float* __restrict__ x,
                                                 const float* __restrict__ w,
                                                 const float* __restrict__ bb,
                                                 float* __restrict__ out, int t0) {
    int tl = blockIdx.x;
    int tg = t0 + tl;
    int src = (tg & ~4095) | ((tg + SH) & 4095);
    int c = threadIdx.x;
    float v = x[((size_t)src - t0) * 256 + c];   // x already offset so row index is src-t0... see launch

    float s1 = v, s2 = v * v;
    #pragma unroll
    for (int o = 32; o > 0; o >>= 1) {
        s1 += __shfl_down(s1, o);
        s2 += __shfl_down(s2, o);
    }
    __shared__ float p1[4], p2[4], stats[2];
    int wid = c >> 6, lane = c & 63;
    if (lane == 0) { p1[wid] = s1; p2[wid] = s2; }
    __syncthreads();
    if (c == 0) {
        float a = p1[0] + p1[1] + p1[2] + p1[3];
        float q = p2[0] + p2[1] + p2[2] + p2[3];
        float mean = a * (1.0f / 256.0f);
        float var = q * (1.0f / 256.0f) - mean * mean;
        stats[0] = mean;
        stats[1] = rsqrtf(var + 1e-5f);
    }
    __syncthreads();
    float y = (v - stats[0]) * stats[1] * w[c] + bb[c];
    out[(size_t)tl * 256 + c] = y;
}

// ---------------- Generic GEMM: C = A[TC,K] @ W[Nc,K]^T + bias ----------------
// MODE 0: C[local r*Nc+col] = v                         (qkv / fc1)
// MODE 1: C[local] = v + res[local]                     (lepe accumulate into attn)
// MODE 2: C[drl*256+col] = v + res[(t0+drl)*256+col]    (proj + reverse-roll + residual -> x1)
// MODE 3: C[(t0+r)*256+col] = v + res[r*256+col]        (fc2 + residual -> d_out)
// ACT 1: exact GELU.  LEPE 1: A built on the fly from v-slice of qkv (3-tap im2col).
template <int MODE, int ACT, int LEPE>
__global__ __launch_bounds__(256) void gemm_kernel(
    const float* __restrict__ A, const float* __restrict__ W,
    const float* __restrict__ bias, float* __restrict__ C,
    const float* __restrict__ res, int t0, int Nc, int K) {
    __shared__ float As[32][64];
    __shared__ float Bs[32][64];
    const int tid = threadIdx.x;
    const int m0 = blockIdx.x * 64, n0 = blockIdx.y * 64;
    const int lr = tid >> 2;          // 0..63
    const int lk = (tid & 3) << 3;    // 0,8,16,24
    const int tm = tid & 15, tn = tid >> 4;

    float acc[4][4] = {{0.f,0.f,0.f,0.f},{0.f,0.f,0.f,0.f},
                       {0.f,0.f,0.f,0.f},{0.f,0.f,0.f,0.f}};

    const int m = m0 + lr;
    const float* ap = A + (size_t)m * K + lk;
    const float* wp = W + (size_t)(n0 + lr) * K + lk;

    for (int k0 = 0; k0 < K; k0 += 32) {
        float af[8], bf[8];
        if (LEPE) {
            int tq = m & 63;  // position within 64-token window
            #pragma unroll
            for (int j = 0; j < 8; ++j) {
                int col = k0 + lk + j;      // < 768
                int i = col / 3;
                int tap = col - i * 3;      // 0,1,2
                int tr = tq + tap - 1;
                float val = 0.f;
                if (tr >= 0 && tr < 64)
                    val = A[(size_t)(m + tap - 1) * 768 + 512 + i];
                af[j] = val;
            }
        } else {
            *(float4*)&af[0] = *(const float4*)(ap + k0);
            *(float4*)&af[4] = *(const float4*)(ap + k0 + 4);
        }
        *(float4*)&bf[0] = *(const float4*)(wp + k0);
        *(float4*)&bf[4] = *(const float4*)(wp + k0 + 4);
        __syncthreads();
        #pragma unroll
        for (int j = 0; j < 8; ++j) {
            As[lk + j][lr] = af[j];
            Bs[lk + j][lr] = bf[j];
        }
        __syncthreads();
        #pragma unroll
        for (int kk = 0; kk < 32; ++kk) {
            float4 a4 = *(const float4*)&As[kk][tm << 2];
            float4 b4 = *(const float4*)&Bs[kk][tn << 2];
            float avr[4] = {a4.x, a4.y, a4.z, a4.w};
            float bvr[4] = {b4.x, b4.y, b4.z, b4.w};
            #pragma unroll
            for (int i = 0; i < 4; ++i)
                #pragma unroll
                for (int j = 0; j < 4; ++j) acc[i][j] += avr[i] * bvr[j];
        }
    }

    float bcol[4];
    #pragma unroll
    for (int j = 0; j < 4; ++j) bcol[j] = bias[n0 + (tn << 2) + j];

    #pragma unroll
    for (int i = 0; i < 4; ++i) {
        size_t r = (size_t)m0 + (tm << 2) + i;      // chunk-local row
        #pragma unroll
        for (int j = 0; j < 4; ++j) {
            float v = acc[i][j] + bcol[j];
            if (ACT == 1) v = 0.5f * v * (1.0f + erff(v * 0.70710678118654752f));
            size_t col = (size_t)n0 + (tn << 2) + j;
            if (MODE == 0) {
                C[r * Nc + col] = v;
            } else if (MODE == 1) {
                size_t idx = r * Nc + col;
                C[idx] = v + res[idx];
            } else if (MODE == 2) {
                size_t drl = (r & ~(size_t)4095) | ((r + SHF) & 4095);
                C[drl * 256 + col] = v + res[((size_t)t0 + drl) * 256 + col];
            } else {
                C[((size_t)t0 + r) * 256 + col] = v + res[r * 256 + col];
            }
        }
    }
}

// ---------------- Attention: one wave per (window, head), chunk-local ----------------
__global__ __launch_bounds__(64) void attn_kernel(const float* __restrict__ qkv,
                                                  const float* __restrict__ mask,
                                                  float* __restrict__ outb) {
    int w = blockIdx.x >> 3;   // chunk-local window
    int h = blockIdx.x & 7;
    int q = threadIdx.x;       // 0..63
    __shared__ float Ks[64][32];
    __shared__ float Vs[64][32];

    const float* kp = qkv + ((size_t)(w * 64 + q)) * 768 + 256 + h * 32;
    const float* vp = kp + 256;
    #pragma unroll
    for (int d = 0; d < 32; d += 4) {
        *(float4*)&Ks[q][d] = *(const float4*)(kp + d);
        *(float4*)&Vs[q][d] = *(const float4*)(vp + d);
    }
    __syncthreads();

    float qreg[32];
    const float* qp = qkv + ((size_t)(w * 64 + q)) * 768 + h * 32;
    #pragma unroll
    for (int d = 0; d < 4; ++d)
        *(float4*)&qreg[d * 4] = *(const float4*)(qp + d * 4);
    #pragma unroll
    for (int d = 16; d < 32; d += 4)
        *(float4*)&qreg[d] = *(const float4*)(qp + d);
    #pragma unroll
    for (int d = 0; d < 32; ++d) qreg[d] *= SCALE;

    int nw = w & 63;  // window index within batch (chunk is whole batches)
    const float* mrow = mask + ((size_t)nw * 64 + q) * 64;

    float s[64];
    float mx = -1e30f;
    for (int k = 0; k < 64; ++k) {
        const float4* kr = (const float4*)&Ks[k][0];
        float acc = 0.f;
        #pragma unroll
        for (int d4 = 0; d4 < 8; ++d4) {
            float4 kv = kr[d4];
            acc += qreg[d4 * 4 + 0] * kv.x + qreg[d4 * 4 + 1] * kv.y +
                   qreg[d4 * 4 + 2] * kv.z + qreg[d4 * 4 + 3] * kv.w;
        }
        acc += mrow[k];
        s[k] = acc;
        mx = fmaxf(mx, acc);
    }
    float l = 0.f;
    for (int k = 0; k < 64; ++k) {
        s[k] = __expf(s[k] - mx);
        l += s[k];
    }
    float inv = 1.0f / l;

    float o[32];
    #pragma unroll
    for (int d = 0; d < 32; ++d) o[d] = 0.f;
    for (int k = 0; k < 64; ++k) {
        float p = s[k];
        const float4* vr = (const float4*)&Vs[k][0];
        #pragma unroll
        for (int d4 = 0; d4 < 8; ++d4) {
            float4 vv = vr[d4];
            o[d4 * 4 + 0] += p * vv.x;
            o[d4 * 4 + 1] += p * vv.y;
            o[d4 * 4 + 2] += p * vv.z;
            o[d4 * 4 + 3] += p * vv.w;
        }
    }
    float* op = outb + ((size_t)(w * 64 + q)) * 256 + h * 32;
    #pragma unroll
    for (int d = 0; d < 32; ++d) op[d] = o[d] * inv;
}

extern "C" void kernel_launch(void* const* d_in, const int* in_sizes, int n_in,
                              void* d_out, int out_size, void* d_ws, size_t ws_size,
                              hipStream_t stream) {
    const float* x     = (const float*)d_in[0];
    const float* mask  = (const float*)d_in[1];
    const float* n1w   = (const float*)d_in[2];
    const float* n1b   = (const float*)d_in[3];
    const float* qkvw  = (const float*)d_in[4];
    const float* qkvbi = (const float*)d_in[5];
    const float* posw  = (const float*)d_in[6];
    const float* posb  = (const float*)d_in[7];
    const float* projw = (const float*)d_in[8];
    const float* projb = (const float*)d_in[9];
    const float* n2w   = (const float*)d_in[10];
    const float* n2b   = (const float*)d_in[11];
    const float* fc1w  = (const float*)d_in[12];
    const float* fc1b  = (const float*)d_in[13];
    const float* fc2w  = (const float*)d_in[14];
    const float* fc2b  = (const float*)d_in[15];

    // chunk = CB batches of 4096 tokens; fp32 scratch = TC*7168 bytes:
    //   [0, TC*1024)        hs / h2   (f32 TCx256)
    //   [TC*1024, TC*2048)  attn out  (f32 TCx256)
    //   [TC*2048, TC*3072)  x1        (f32 TCx256)
    //   [TC*3072, TC*7168)  qkv (TCx768) / mid (TCx1024)  (aliased, disjoint liveness)
    int CB = 32;
    while (CB > 1 && (size_t)CB * 4096 * 7168 > ws_size) CB >>= 1;
    const int TC = CB * 4096;

    char* ws = (char*)d_ws;
    float* hs   = (float*)ws;
    float* attn = (float*)(ws + (size_t)TC * 1024);
    float* x1   = (float*)(ws + (size_t)TC * 2048);
    float* qkv  = (float*)(ws + (size_t)TC * 3072);
    float* mid  = qkv;

    for (int t0 = 0; t0 < TT; t0 += TC) {
        // 1. LN1 + roll(-32): pass x offset by t0 rows so kernel indexes chunk-local,
        //    but roll must wrap inside each global batch -> t0 is a multiple of 4096,
        //    so (tg&~4095)|((tg+32)&4095) - t0 == (tl&~4095)|((tl+32)&4095). Use x+t0*256.
        ln_kernel<SHF><<<TC, 256, 0, stream>>>(x + (size_t)t0 * 256, n1w, n1b, hs, 0);
        // 2. QKV GEMM
        gemm_kernel<0, 0, 0><<<dim3(TC / 64, 12), 256, 0, stream>>>(
            hs, qkvw, qkvbi, qkv, nullptr, 0, 768, 256);
        // 3. windowed attention
        attn_kernel<<<(TC / 64) * 8, 64, 0, stream>>>(qkv, mask, attn);
        // 4. LePE conv-as-GEMM (A im2col'd on the fly), accumulate into attn
        gemm_kernel<1, 0, 1><<<dim3(TC / 64, 4), 256, 0, stream>>>(
            qkv, posw, posb, attn, attn, 0, 256, 768);
        // 5. proj + window-reverse + roll(+32) + residual -> x1
        gemm_kernel<2, 0, 0><<<dim3(TC / 64, 4), 256, 0, stream>>>(
            attn, projw, projb, x1, x, t0, 256, 256);
        // 6. LN2 (x1 chunk-local, no shift)
        ln_kernel<0><<<TC, 256, 0, stream>>>(x1, n2w, n2b, hs, 0);
        // 7. FC1 + exact GELU
        gemm_kernel<0, 1, 0><<<dim3(TC / 64, 16), 256, 0, stream>>>(
            hs, fc1w, fc1b, mid, nullptr, 0, 1024, 256);
        // 8. FC2 + residual -> out (global rows)
        gemm_kernel<3, 0, 0><<<dim3(TC / 64, 4), 256, 0, stream>>>(
            mid, fc2w, fc2b, (float*)d_out, x1, t0, 256, 1024);
    }
}

// Round 4
// 1486.262 us; speedup vs baseline: 3.2265x; 3.2265x over previous
//
#include <hip/hip_runtime.h>

typedef unsigned short u16;
typedef unsigned int   u32;
typedef short bf16x8 __attribute__((ext_vector_type(8)));
typedef float f32x4  __attribute__((ext_vector_type(4)));

#define TT   131072         // B*N tokens
#define SCALE 0.17677669529663687f

__device__ __forceinline__ float bf2f(u32 u) {
    u32 v = u << 16;
    float f;
    __builtin_memcpy(&f, &v, 4);
    return f;
}
__device__ __forceinline__ u16 f2bf(float f) {
    u32 v;
    __builtin_memcpy(&v, &f, 4);
    u32 r = v + 0x7fffu + ((v >> 16) & 1u);
    return (u16)(r >> 16);
}
__device__ __forceinline__ void unp8(uint4 u, float* f) {
    f[0] = bf2f(u.x & 0xffffu); f[1] = bf2f(u.x >> 16);
    f[2] = bf2f(u.y & 0xffffu); f[3] = bf2f(u.y >> 16);
    f[4] = bf2f(u.z & 0xffffu); f[5] = bf2f(u.z >> 16);
    f[6] = bf2f(u.w & 0xffffu); f[7] = bf2f(u.w >> 16);
}

// async global->LDS, 16B per lane, dest = uniform base + lane*16
#define GLD16(g, l)                                                           \
    __builtin_amdgcn_global_load_lds(                                         \
        (const __attribute__((address_space(1))) void*)(g),                   \
        (__attribute__((address_space(3))) void*)(l), 16, 0, 0)

// ---------------- weight fp32 -> bf16 conversion (once per launch) ----------
// layout in dst (elements): qkvw[0,196608) posw[196608,393216) projw[393216,458752)
//                           fc1w[458752,720896) fc2w[720896,983040)
__global__ __launch_bounds__(256) void cvt_kernel(
    const float* __restrict__ qkvw, const float* __restrict__ posw,
    const float* __restrict__ projw, const float* __restrict__ fc1w,
    const float* __restrict__ fc2w, u16* __restrict__ dst) {
    int i = blockIdx.x * 256 + threadIdx.x;   // grid exactly covers 983040
    float v;
    if (i < 196608)       v = qkvw[i];
    else if (i < 393216)  v = posw[i - 196608];
    else if (i < 458752)  v = projw[i - 393216];
    else if (i < 720896)  v = fc1w[i - 458752];
    else                  v = fc2w[i - 720896];
    dst[i] = f2bf(v);
}

// ---------------- LayerNorm (+optional intra-batch roll), fp32 in -> bf16 out
template <int SH>
__global__ __launch_bounds__(256) void ln_kernel(const float* __restrict__ x,
                                                 const float* __restrict__ w,
                                                 const float* __restrict__ bb,
                                                 u16* __restrict__ out) {
    int tl = blockIdx.x;
    int src = (tl & ~4095) | ((tl + SH) & 4095);
    int c = threadIdx.x;
    float v = x[(size_t)src * 256 + c];

    float s1 = v, s2 = v * v;
    #pragma unroll
    for (int o = 32; o > 0; o >>= 1) {
        s1 += __shfl_down(s1, o);
        s2 += __shfl_down(s2, o);
    }
    __shared__ float p1[4], p2[4], stats[2];
    int wid = c >> 6, lane = c & 63;
    if (lane == 0) { p1[wid] = s1; p2[wid] = s2; }
    __syncthreads();
    if (c == 0) {
        float a = p1[0] + p1[1] + p1[2] + p1[3];
        float q = p2[0] + p2[1] + p2[2] + p2[3];
        float mean = a * (1.0f / 256.0f);
        float var = q * (1.0f / 256.0f) - mean * mean;
        stats[0] = mean;
        stats[1] = rsqrtf(var + 1e-5f);
    }
    __syncthreads();
    float y = (v - stats[0]) * stats[1] * w[c] + bb[c];
    out[(size_t)tl * 256 + c] = f2bf(y);
}

// ---------------- MFMA GEMM: C = A[M,K]bf16 @ W[Nc,K]bf16^T + bias ----------
// 128x128 tile, BK=32, 4 waves (2x2 of 64x64), 16x16x32 bf16 MFMA, fp32 acc.
// MODE 0: Cb[r*Nc+c]  = v                         (qkv / fc1)
// MODE 1: Cb[idx]    += v                         (lepe accumulate into attn)
// MODE 2: Cf[drl*256+c] = v + resf[drl*256+c]     (proj + reverse-roll + residual -> x1)
// MODE 3: Cf[r*256+c]   = v + resf[r*256+c]       (fc2 + residual -> d_out chunk)
// ACT 1: exact GELU
template <int MODE, int ACT>
__global__ __launch_bounds__(256) void mgemm(
    const u16* __restrict__ A, const u16* __restrict__ W,
    const float* __restrict__ bias, u16* __restrict__ Cb,
    float* __restrict__ Cf, const float* __restrict__ resf,
    int Nc, int K) {
    __shared__ u16 As[128 * 32];
    __shared__ u16 Bs[128 * 32];
    const int tid = threadIdx.x;
    const int m0 = blockIdx.x * 128, n0 = blockIdx.y * 128;
    const int w4 = tid >> 6, lane = tid & 63;
    // staging: wave w covers rows 32w..32w+31 of the tile; lane -> (row, 16B group)
    const int srow = 32 * w4 + (lane >> 2);
    const int scol = (lane & 3) * 8;                 // element offset in row
    const u16* ag = A + (size_t)(m0 + srow) * K + scol;
    const u16* bg = W + (size_t)(n0 + srow) * K + scol;
    u16* lA = As + w4 * 1024;                        // 32 rows * 32 elem
    u16* lB = Bs + w4 * 1024;
    // fragments
    const int frow = lane & 15, fk = (lane >> 4) * 8;
    const int am = (w4 & 1) * 64, bn = (w4 >> 1) * 64;

    f32x4 acc[4][4];
    #pragma unroll
    for (int i = 0; i < 4; ++i)
        #pragma unroll
        for (int j = 0; j < 4; ++j) acc[i][j] = (f32x4){0.f, 0.f, 0.f, 0.f};

    for (int k0 = 0; k0 < K; k0 += 32) {
        __syncthreads();
        GLD16(ag + k0, lA);
        GLD16(ag + k0 + (size_t)16 * K, lA + 512);
        GLD16(bg + k0, lB);
        GLD16(bg + k0 + (size_t)16 * K, lB + 512);
        __syncthreads();
        bf16x8 af[4], bfr[4];
        #pragma unroll
        for (int mi = 0; mi < 4; ++mi)
            af[mi] = *(const bf16x8*)&As[(am + mi * 16 + frow) * 32 + fk];
        #pragma unroll
        for (int ni = 0; ni < 4; ++ni)
            bfr[ni] = *(const bf16x8*)&Bs[(bn + ni * 16 + frow) * 32 + fk];
        #pragma unroll
        for (int mi = 0; mi < 4; ++mi)
            #pragma unroll
            for (int ni = 0; ni < 4; ++ni)
                acc[mi][ni] = __builtin_amdgcn_mfma_f32_16x16x32_bf16(
                    af[mi], bfr[ni], acc[mi][ni], 0, 0, 0);
    }

    // epilogue; C/D layout: col = lane&15, row = (lane>>4)*4 + reg
    const int erow = am + ((lane >> 4) << 2);
    const int ecol = bn + (lane & 15);
    #pragma unroll
    for (int ni = 0; ni < 4; ++ni) {
        int c = n0 + ecol + ni * 16;
        float bv = bias[c];
        #pragma unroll
        for (int mi = 0; mi < 4; ++mi) {
            #pragma unroll
            for (int reg = 0; reg < 4; ++reg) {
                int r = m0 + erow + mi * 16 + reg;
                float v = acc[mi][ni][reg] + bv;
                if (ACT == 1) v = 0.5f * v * (1.0f + erff(v * 0.70710678118654752f));
                if (MODE == 0) {
                    Cb[(size_t)r * Nc + c] = f2bf(v);
                } else if (MODE == 1) {
                    size_t idx = (size_t)r * Nc + c;
                    Cb[idx] = f2bf(v + bf2f(Cb[idx]));
                } else if (MODE == 2) {
                    size_t drl = (size_t)((r & ~4095) | ((r + 32) & 4095));
                    Cf[drl * 256 + c] = v + resf[drl * 256 + c];
                } else {
                    Cf[(size_t)r * 256 + c] = v + resf[(size_t)r * 256 + c];
                }
            }
        }
    }
}

// ---------------- im2col for LePE: avp[t, i*3+tap] = v[t+tap-1, i] ----------
__global__ __launch_bounds__(256) void avp_kernel(const u16* __restrict__ qkv,
                                                  u16* __restrict__ avp) {
    int t = blockIdx.x;
    int i = threadIdx.x;
    int tq = t & 63;
    const u16* vbase = qkv + (size_t)t * 768 + 512;
    u16 vm1 = (tq > 0) ? vbase[i - 768] : (u16)0;
    u16 v0 = vbase[i];
    u16 vp1 = (tq < 63) ? vbase[i + 768] : (u16)0;
    u16* o = avp + (size_t)t * 768 + i * 3;
    o[0] = vm1;
    o[1] = v0;
    o[2] = vp1;
}

// ---------------- Attention: one wave per (window, head) --------------------
__global__ __launch_bounds__(64) void attn_kernel(const u16* __restrict__ qkv,
                                                  const float* __restrict__ mask,
                                                  u16* __restrict__ outb) {
    int w = blockIdx.x >> 3;   // chunk-local window
    int h = blockIdx.x & 7;
    int q = threadIdx.x;       // 0..63
    __shared__ float Ks[64][32];
    __shared__ float Vs[64][32];

    const u16* kp = qkv + ((size_t)(w * 64 + q)) * 768 + 256 + h * 32;
    const u16* vp = kp + 256;
    {
        float tmp[8];
        #pragma unroll
        for (int d = 0; d < 32; d += 8) {
            unp8(*(const uint4*)(kp + d), tmp);
            #pragma unroll
            for (int j = 0; j < 8; ++j) Ks[q][d + j] = tmp[j];
            unp8(*(const uint4*)(vp + d), tmp);
            #pragma unroll
            for (int j = 0; j < 8; ++j) Vs[q][d + j] = tmp[j];
        }
    }
    __syncthreads();

    float qreg[32];
    const u16* qp = qkv + ((size_t)(w * 64 + q)) * 768 + h * 32;
    #pragma unroll
    for (int d = 0; d < 32; d += 8) unp8(*(const uint4*)(qp + d), &qreg[d]);
    #pragma unroll
    for (int d = 0; d < 32; ++d) qreg[d] *= SCALE;

    int nw = w & 63;  // window index within batch (chunks are whole batches)
    const float* mrow = mask + ((size_t)nw * 64 + q) * 64;

    float s[64];
    float mx = -1e30f;
    for (int k = 0; k < 64; ++k) {
        const float4* kr = (const float4*)&Ks[k][0];
        float acc = 0.f;
        #pragma unroll
        for (int d4 = 0; d4 < 8; ++d4) {
            float4 kv = kr[d4];
            acc += qreg[d4 * 4 + 0] * kv.x + qreg[d4 * 4 + 1] * kv.y +
                   qreg[d4 * 4 + 2] * kv.z + qreg[d4 * 4 + 3] * kv.w;
        }
        acc += mrow[k];
        s[k] = acc;
        mx = fmaxf(mx, acc);
    }
    float l = 0.f;
    for (int k = 0; k < 64; ++k) {
        s[k] = __expf(s[k] - mx);
        l += s[k];
    }
    float inv = 1.0f / l;

    float o[32];
    #pragma unroll
    for (int d = 0; d < 32; ++d) o[d] = 0.f;
    for (int k = 0; k < 64; ++k) {
        float p = s[k];
        const float4* vr = (const float4*)&Vs[k][0];
        #pragma unroll
        for (int d4 = 0; d4 < 8; ++d4) {
            float4 vv = vr[d4];
            o[d4 * 4 + 0] += p * vv.x;
            o[d4 * 4 + 1] += p * vv.y;
            o[d4 * 4 + 2] += p * vv.z;
            o[d4 * 4 + 3] += p * vv.w;
        }
    }
    u16* op = outb + ((size_t)(w * 64 + q)) * 256 + h * 32;
    #pragma unroll
    for (int d = 0; d < 32; ++d) op[d] = f2bf(o[d] * inv);
}

extern "C" void kernel_launch(void* const* d_in, const int* in_sizes, int n_in,
                              void* d_out, int out_size, void* d_ws, size_t ws_size,
                              hipStream_t stream) {
    const float* x     = (const float*)d_in[0];
    const float* mask  = (const float*)d_in[1];
    const float* n1w   = (const float*)d_in[2];
    const float* n1b   = (const float*)d_in[3];
    const float* qkvw  = (const float*)d_in[4];
    const float* qkvbi = (const float*)d_in[5];
    const float* posw  = (const float*)d_in[6];
    const float* posb  = (const float*)d_in[7];
    const float* projw = (const float*)d_in[8];
    const float* projb = (const float*)d_in[9];
    const float* n2w   = (const float*)d_in[10];
    const float* n2b   = (const float*)d_in[11];
    const float* fc1w  = (const float*)d_in[12];
    const float* fc1b  = (const float*)d_in[13];
    const float* fc2w  = (const float*)d_in[14];
    const float* fc2b  = (const float*)d_in[15];

    // per-chunk scratch, TC tokens (CB whole batches so roll stays chunk-local):
    //   hs/h2 : [0,        TC*512)   bf16 TCx256
    //   attn  : [TC*512,   TC*1024)  bf16 TCx256
    //   x1    : [TC*1024,  TC*2048)  fp32 TCx256
    //   qkv   : [TC*2048,  TC*3584)  bf16 TCx768
    //   avp   : [TC*3584,  TC*5120)  bf16 TCx768
    //   mid   : aliases [TC*2048, TC*4096) bf16 TCx1024 (qkv+avp dead by then)
    //   wbf   : [TC*5120, +1966080)  bf16 weights
    int CB = 32;
    while (CB > 1 && (size_t)CB * 4096 * 5120 + 1966080ull > ws_size) CB >>= 1;
    const int TC = CB * 4096;

    char* ws = (char*)d_ws;
    u16*   hs   = (u16*)ws;
    u16*   attn = (u16*)(ws + (size_t)TC * 512);
    float* x1   = (float*)(ws + (size_t)TC * 1024);
    u16*   qkv  = (u16*)(ws + (size_t)TC * 2048);
    u16*   avp  = (u16*)(ws + (size_t)TC * 3584);
    u16*   mid  = qkv;
    u16*   wbf  = (u16*)(ws + (size_t)TC * 5120);
    u16* qkvw_b = wbf;
    u16* posw_b = wbf + 196608;
    u16* projw_b = wbf + 393216;
    u16* fc1w_b = wbf + 458752;
    u16* fc2w_b = wbf + 720896;

    cvt_kernel<<<3840, 256, 0, stream>>>(qkvw, posw, projw, fc1w, fc2w, wbf);

    for (int t0 = 0; t0 < TT; t0 += TC) {
        const float* xc = x + (size_t)t0 * 256;
        // 1. LN1 + roll(-32)   (t0 multiple of 4096 -> roll chunk-local)
        ln_kernel<32><<<TC, 256, 0, stream>>>(xc, n1w, n1b, hs);
        // 2. QKV GEMM (bf16 MFMA)
        mgemm<0, 0><<<dim3(TC / 128, 6), 256, 0, stream>>>(
            hs, qkvw_b, qkvbi, qkv, nullptr, nullptr, 768, 256);
        // 3. windowed attention
        attn_kernel<<<(TC / 64) * 8, 64, 0, stream>>>(qkv, mask, attn);
        // 4a. im2col of V for LePE
        avp_kernel<<<TC, 256, 0, stream>>>(qkv, avp);
        // 4b. LePE conv-as-GEMM, accumulate into attn
        mgemm<1, 0><<<dim3(TC / 128, 2), 256, 0, stream>>>(
            avp, posw_b, posb, attn, nullptr, nullptr, 256, 768);
        // 5. proj + window-reverse + roll(+32) + residual -> x1 (fp32)
        mgemm<2, 0><<<dim3(TC / 128, 2), 256, 0, stream>>>(
            attn, projw_b, projb, nullptr, x1, xc, 256, 256);
        // 6. LN2
        ln_kernel<0><<<TC, 256, 0, stream>>>(x1, n2w, n2b, hs);
        // 7. FC1 + exact GELU
        mgemm<0, 1><<<dim3(TC / 128, 8), 256, 0, stream>>>(
            hs, fc1w_b, fc1b, mid, nullptr, nullptr, 1024, 256);
        // 8. FC2 + residual -> d_out (fp32)
        mgemm<3, 0><<<dim3(TC / 128, 2), 256, 0, stream>>>(
            mid, fc2w_b, fc2b, nullptr, (float*)d_out + (size_t)t0 * 256, x1,
            256, 1024);
    }
}